// Round 13
// baseline (264.185 us; speedup 1.0000x reference)
//
#include <hip/hip_runtime.h>
#include <stdint.h>

#define Bb 8
#define Cc 256
#define Nn 2304
#define PJT 18   // proj: 128-token tiles
#define QT 18    // attn: 128-query tiles
#define KSPLIT 3
#define TPS 24   // 32-key tiles per split (72 total / KSPLIT)
#define L2E 1.44269504088896f
#define DEFER_THR 8.0f

#define AS1 __attribute__((address_space(1)))
#define AS3 __attribute__((address_space(3)))

typedef unsigned short u16;
typedef unsigned int u32;
typedef _Float16 h16;
typedef h16  h16x8 __attribute__((ext_vector_type(8)));
typedef u16  u16x8 __attribute__((ext_vector_type(8)));
typedef u16  u16x4 __attribute__((ext_vector_type(4)));
typedef u32  u32x4 __attribute__((ext_vector_type(4)));
typedef float f32x4 __attribute__((ext_vector_type(4)));
typedef float f32x2 __attribute__((ext_vector_type(2)));

static __device__ __forceinline__ u16 f2h(float f) {
  return __builtin_bit_cast(u16, (h16)f);   // RTN
}
static __device__ __forceinline__ float h2f(u16 v) {
  return (float)__builtin_bit_cast(h16, v);
}
static __device__ __forceinline__ h16x8 ash(u16x8 v) {
  return __builtin_bit_cast(h16x8, v);
}
static __device__ __forceinline__ f32x4 mfma16(u16x8 a, u16x8 b, f32x4 c) {
  return __builtin_amdgcn_mfma_f32_16x16x32_f16(ash(a), ash(b), c, 0, 0, 0);
}
// pack 2 f32 -> 2 f16 (RTZ), as one u32 (P values only; P in [0, e^8])
static __device__ __forceinline__ u32 pkf16(float a, float b) {
  return __builtin_bit_cast(u32, __builtin_amdgcn_cvt_pkrtz(a, b));
}

// ---------------------------------------------------------------------------
// Prep v14 (verified r12): W fp32->fp16; x,y transpose to token-major fp16.
// ---------------------------------------------------------------------------
__global__ void prep_kernel(const float* __restrict__ Wq,
                            const float* __restrict__ Wk,
                            const float* __restrict__ Wv,
                            const float* __restrict__ x,
                            const float* __restrict__ y,
                            u16* __restrict__ Wf,
                            u16* __restrict__ Xt,
                            u16* __restrict__ Yt)
{
  const int bid = blockIdx.x;
  const int t   = threadIdx.x;
  if (bid < 96) {
    const int tid = bid * 256 + t;
    const int m   = tid >> 13;
    const int off = (tid & 8191) * 8;
    const float* src = (m == 0) ? Wq : (m == 1) ? Wk : Wv;
    const f32x4 a = *(const f32x4*)(src + off);
    const f32x4 c = *(const f32x4*)(src + off + 4);
    u16x8 o;
#pragma unroll
    for (int j = 0; j < 4; ++j) { o[j] = f2h(a[j]); o[j + 4] = f2h(c[j]); }
    *(u16x8*)(Wf + (size_t)m * 65536 + off) = o;
    return;
  }
  // transpose path: 2304 blocks = 2 tensors x 8 b x 36 tok-tiles x 4 c-tiles
  __shared__ u16 sT[64 * 64];   // 8 KB
  const int id2  = bid - 96;
  const float* src = (id2 < 1152) ? x : y;
  u16* dst         = (id2 < 1152) ? Xt : Yt;
  const int id3  = id2 % 1152;
  const int b    = id3 / 144;        // 144 = 36*4
  const int rem  = id3 % 144;
  const int tok0 = (rem >> 2) * 64;
  const int c0   = (rem & 3) * 64;

#pragma unroll
  for (int i = 0; i < 4; ++i) {
    const int id4 = i * 256 + t;
    const int cl  = id4 >> 4;        // channel-in-tile 0..63
    const int t4  = id4 & 15;        // token-quad 0..15
    const f32x4 v = *(const f32x4*)(src + ((size_t)b * Cc + c0 + cl) * Nn + tok0 + t4 * 4);
#pragma unroll
    for (int j = 0; j < 4; ++j) {
      const int tok = t4 * 4 + j;
      sT[tok * 64 + (cl ^ ((t4 & 7) << 3))] = f2h(v[j]);  // t4 == tok>>2
    }
  }
  __syncthreads();
#pragma unroll
  for (int i = 0; i < 2; ++i) {
    const int id5 = i * 256 + t;
    const int tok = id5 >> 3;        // 0..63
    const int c8  = (id5 & 7) * 8;
    const u16x8 vv = *(const u16x8*)(sT + tok * 64 + (c8 ^ (((tok >> 2) & 7) << 3)));
    *(u16x8*)(dst + ((size_t)b * Nn + tok0 + tok) * Cc + c0 + c8) = vv;
  }
}

// ---------------------------------------------------------------------------
// Projection v14 (verified r12): 4-round dbuf DMA-staged W, two 64-token
// groups per wave, contiguous af loads from Xt/Yt, coalesced LDS-bounce
// epilogue.
// ---------------------------------------------------------------------------
__global__ __launch_bounds__(256, 2) void proj_kernel(
    const u16* __restrict__ Xt, const u16* __restrict__ Yt,
    const u16* __restrict__ Wf,
    const float* __restrict__ bq, const float* __restrict__ bk,
    const float* __restrict__ bv,
    u16* __restrict__ Qf, u16* __restrict__ Kf, u16* __restrict__ Vf)
{
  __shared__ u16 sW[2][64 * 256];   // 2 x 32 KB
  const int t    = threadIdx.x;
  const int b    = blockIdx.x;
  const int q0   = blockIdx.y * 128;
  const int z    = blockIdx.z;
  const int lane = t & 63;
  const int w    = t >> 6;
  const int quad = lane >> 4;
  const int l15  = lane & 15;

  const u16* WZ = Wf + (size_t)z * 65536;

  const int rbase = 2 * w + (lane >> 5);
  const int wcol  = ((lane & 31) ^ rbase) << 3;

  auto stage = [&](int rg, int buf) {
#pragma unroll
    for (int it = 0; it < 8; ++it) {
      __builtin_amdgcn_global_load_lds(
          (const AS1 void*)(WZ + (size_t)(rg * 64 + rbase + 8 * it) * 256 + wcol),
          (AS3 void*)&sW[buf][(w + 4 * it) * 512], 16, 0, 0);
    }
  };

  stage(0, 0);   // overlap W DMA with the token-fragment loads below

  // token fragments, two 64-token groups: contiguous u16x8 from Xt/Yt
  const u16* S = (z == 0) ? Xt : Yt;
  u16x8 af[2][8];
#pragma unroll
  for (int g = 0; g < 2; ++g) {
    const size_t row = ((size_t)b * Nn + q0 + g * 64 + w * 16 + l15) * Cc;
#pragma unroll
    for (int kc = 0; kc < 8; ++kc)
      af[g][kc] = *(const u16x8*)(S + row + kc * 32 + quad * 8);
  }

  f32x4 acc[2][16];
#pragma unroll
  for (int g = 0; g < 2; ++g)
#pragma unroll
    for (int i = 0; i < 16; ++i) acc[g][i] = (f32x4){0.f, 0.f, 0.f, 0.f};

  int cur = 0;
#pragma unroll 1
  for (int rg = 0; rg < 4; ++rg) {   // 64 c_out rows per round
    __builtin_amdgcn_s_waitcnt(0x0F70);  // vmcnt(0): sW[cur] DMA done
    __syncthreads();                     // visible to all; prev round's reads done
    if (rg + 1 < 4) stage(rg + 1, cur ^ 1);   // hides under this round's compute
#pragma unroll
    for (int cbl = 0; cbl < 4; ++cbl) {
      const int rl = cbl * 16 + l15;   // 0..63
      f32x4 a0 = acc[0][rg * 4 + cbl];
      f32x4 a1 = acc[1][rg * 4 + cbl];
#pragma unroll
      for (int kc = 0; kc < 8; ++kc) {
        const u16x8 bf = *(const u16x8*)(sW[cur] + rl * 256 + (((kc * 4 + quad) ^ (rl & 7)) << 3));
        if (z < 2) {
          a0 = mfma16(af[0][kc], bf, a0);
          a1 = mfma16(af[1][kc], bf, a1);
        } else {
          a0 = mfma16(bf, af[0][kc], a0);
          a1 = mfma16(bf, af[1][kc], a1);
        }
      }
      acc[0][rg * 4 + cbl] = a0;
      acc[1][rg * 4 + cbl] = a1;
    }
    cur ^= 1;
  }

  // ---- coalesced epilogues via LDS bounce (sT = 32 KB within sW) ----
  u16* sT = &sW[0][0];
  if (z < 2) {
    const float* bias = (z == 0) ? bq : bk;
    u16* O = (z == 0) ? Qf : Kf;
#pragma unroll
    for (int g = 0; g < 2; ++g) {
      __syncthreads();   // prior users of sW done (compute rounds / prev g copy)
#pragma unroll
      for (int cb = 0; cb < 16; ++cb) {
        const int col = cb * 16 + l15;
        const float bs = bias[col];
#pragma unroll
        for (int r = 0; r < 4; ++r) {
          const int row = w * 16 + quad * 4 + r;   // token-in-tile 0..63
          sT[row * 256 + (col ^ ((row & 7) << 3))] = f2h(acc[g][cb][r] + bs);
        }
      }
      __syncthreads();
      const size_t ob = ((size_t)b * Nn + q0 + g * 64) * Cc;
#pragma unroll
      for (int i = 0; i < 8; ++i) {
        const int lin = i * 256 + t;
        const int row = lin >> 5, ch = lin & 31;
        const u16x8 v = *(const u16x8*)(sT + row * 256 + ((ch ^ (row & 7)) << 3));
        *(u16x8*)(O + ob + (size_t)lin * 8) = v;
      }
    }
  } else {
#pragma unroll
    for (int g = 0; g < 2; ++g) {
      __syncthreads();
#pragma unroll
      for (int cb = 0; cb < 16; ++cb) {
#pragma unroll
        for (int r = 0; r < 4; ++r) {
          const int c = cb * 16 + quad * 4 + r;    // c_out row 0..255
          const int col = w * 16 + l15;            // token-in-tile 0..63
          sT[c * 64 + (col ^ ((c & 7) << 3))] = f2h(acc[g][cb][r] + bv[c]);
        }
      }
      __syncthreads();
#pragma unroll
      for (int i = 0; i < 8; ++i) {
        const int lin = i * 256 + t;
        const int row = lin >> 3, g8 = lin & 7;
        const u16x8 v = *(const u16x8*)(sT + row * 64 + ((g8 ^ (row & 7)) << 3));
        *(u16x8*)(Vf + ((size_t)b * Cc + row) * Nn + q0 + g * 64 + g8 * 8) = v;
      }
    }
  }
}

// ---------------------------------------------------------------------------
// Flash attention v15 = v13 with K read DIRECTLY from global (sK deleted):
// the K A-fragment addresses depend only on l15 (all 4 waves read identical
// sK data -> 4x LDS broadcast amplification on an LDS-read-bound kernel).
// Direct per-lane u16x8 loads from Kf halve LDS traffic; all waves issue
// identical addresses (L2 broadcast); quads of equal l15 share 64B lines.
// kappa permutation becomes per-thread row constants: krow0=8*(l15>>2)+
// (l15&3), krow1=krow0+4 (same S->PV slot mapping as the verified DMA
// permutation). V staging/dbuf/softmax/PV/epilogue byte-identical to v13.
// LDS 32 KB; still VGPR-capped at 2 blocks/CU.
// ---------------------------------------------------------------------------
__global__ __launch_bounds__(256, 2) void attn_kernel(
    const u16* __restrict__ Qf, const u16* __restrict__ Kf,
    const u16* __restrict__ Vf, u16* __restrict__ OpH,
    float* __restrict__ Ml)
{
  __shared__ u16 sV[2][256 * 32];   // 2 x 16 KB
  const int t    = threadIdx.x;
  const int b    = blockIdx.x;
  const int q0   = blockIdx.y * 128;
  const int sp   = blockIdx.z;
  const int lane = t & 63;
  const int w    = t >> 6;
  const int quad = lane >> 4;
  const int l15  = lane & 15;
  const int wq0  = q0 + w * 32;

  const u16* Kb = Kf + (size_t)b * Nn * Cc;
  const u16* Vb = Vf + (size_t)b * Cc * Nn;

  // K direct-load geometry: actual key rows for this lane's S/PV slots
  const int krow0 = ((l15 >> 2) << 3) + (l15 & 3);   // keys 8q'+r'
  const size_t kO0 = (size_t)krow0 * Cc + quad * 8;
  const size_t kO1 = kO0 + (size_t)4 * Cc;           // krow1 = krow0 + 4
  const u16* Kt = Kb + (size_t)(sp * TPS * 32) * Cc;

  // V staging geometry (unchanged)
  const int cV   = w * 16 + (lane >> 2);
  const int vcol = ((lane & 3) ^ ((cV >> 1) & 3)) << 3;
  const u16* vp0 = Vb + (size_t)cV * Nn + sp * TPS * 32 + vcol;

  auto stage = [&](int kb, int buf) {
#pragma unroll
    for (int it = 0; it < 4; ++it) {
      __builtin_amdgcn_global_load_lds(
          (const AS1 void*)(vp0 + kb * 32 + (size_t)it * 64 * Nn),
          (AS3 void*)&sV[buf][(w + 4 * it) * 512], 16, 0, 0);
    }
  };

  stage(0, 0);   // overlap with qf loads

  // Q fragments, 2 groups of 16 queries (B-operand; col = lane = query)
  u16x8 qf[2][8];
#pragma unroll
  for (int g = 0; g < 2; ++g) {
    const size_t qrow = ((size_t)b * Nn + wq0 + g * 16 + l15) * Cc;
#pragma unroll
    for (int kc = 0; kc < 8; ++kc)
      qf[g][kc] = *(const u16x8*)(Qf + qrow + kc * 32 + quad * 8);
  }

  f32x4 o[2][16];   // O^T accum per group: c = cb*16+quad*4+r, q = l15
#pragma unroll
  for (int g = 0; g < 2; ++g)
#pragma unroll
    for (int i = 0; i < 16; ++i) o[g][i] = (f32x4){0.f, 0.f, 0.f, 0.f};
  float mrow[2] = {-3e38f, -3e38f};
  float lrow[2] = {0.f, 0.f};

  // PV read swizzle is cb-independent: (c>>1)&3 == (l15>>1)&3
  const int vbase = l15 * 32 + ((quad ^ ((l15 >> 1) & 3)) << 3);

  int cur = 0;
#pragma unroll 1
  for (int kb = 0; kb < TPS; ++kb) {
    __builtin_amdgcn_s_waitcnt(0x0F70);  // vmcnt(0): sV[cur] DMA done
    __syncthreads();                     // visible; prev tile's reads all done

    // ---- S^T = K Q^T: K straight from global (L2-broadcast across waves)
    const u16* Ktile = Kt + (size_t)kb * 32 * Cc;
    f32x4 s[2][2];
    s[0][0] = (f32x4){0.f, 0.f, 0.f, 0.f}; s[0][1] = s[0][0];
    s[1][0] = s[0][0];                      s[1][1] = s[0][0];
#pragma unroll
    for (int kc = 0; kc < 8; ++kc) {
      const u16x8 k0 = *(const u16x8*)(Ktile + kO0 + kc * 32);
      const u16x8 k1 = *(const u16x8*)(Ktile + kO1 + kc * 32);
      s[0][0] = mfma16(k0, qf[0][kc], s[0][0]);
      s[0][1] = mfma16(k1, qf[0][kc], s[0][1]);
      s[1][0] = mfma16(k0, qf[1][kc], s[1][0]);
      s[1][1] = mfma16(k1, qf[1][kc], s[1][1]);
    }

    // ---- prefetch next V tile (lands under softmax+PV)
    if (kb + 1 < TPS) stage(kb + 1, cur ^ 1);

    // ---- lane-local online softmax per group
    u16x8 pf[2];
    float al[2];
    int needany = 0;
#pragma unroll
    for (int g = 0; g < 2; ++g) {
      float mloc = fmaxf(
          fmaxf(fmaxf(s[g][0][0], s[g][0][1]), fmaxf(s[g][0][2], s[g][0][3])),
          fmaxf(fmaxf(s[g][1][0], s[g][1][1]), fmaxf(s[g][1][2], s[g][1][3])));
      mloc = fmaxf(mloc, __shfl_xor(mloc, 16, 64));
      mloc = fmaxf(mloc, __shfl_xor(mloc, 32, 64));
      const bool need = mloc > mrow[g] + DEFER_THR;
      const float mn  = need ? mloc : mrow[g];
      al[g] = need ? exp2f((mrow[g] - mn) * L2E) : 1.f;
      mrow[g] = mn;
      needany |= (int)need;

      float p[8];
      float sum = 0.f;
#pragma unroll
      for (int r = 0; r < 4; ++r) {
        p[r]     = exp2f((s[g][0][r] - mn) * L2E);
        p[4 + r] = exp2f((s[g][1][r] - mn) * L2E);
        sum += p[r] + p[4 + r];
      }
      sum += __shfl_xor(sum, 16, 64);
      sum += __shfl_xor(sum, 32, 64);
      lrow[g] = lrow[g] * al[g] + sum;

      u32x4 pw;
      pw[0] = pkf16(p[0], p[1]);
      pw[1] = pkf16(p[2], p[3]);
      pw[2] = pkf16(p[4], p[5]);
      pw[3] = pkf16(p[6], p[7]);
      pf[g] = __builtin_bit_cast(u16x8, pw);
    }

    if (__any(needany)) {
#pragma unroll
      for (int i = 0; i < 16; ++i) {
#pragma unroll
        for (int r = 0; r < 4; ++r) {
          o[0][i][r] *= al[0];
          o[1][i][r] *= al[1];
        }
      }
    }

    // ---- O^T += V^T P, both groups share vf reads
#pragma unroll
    for (int cb = 0; cb < 16; ++cb) {
      const u16x8 vf = *(const u16x8*)(sV[cur] + cb * 512 + vbase);
      o[0][cb] = mfma16(vf, pf[0], o[0][cb]);
      o[1][cb] = mfma16(vf, pf[1], o[1][cb]);
    }

    cur ^= 1;
  }

  // ---- epilogue: per-split NORMALIZED fp16 partials
  u16* Ob = OpH + ((size_t)sp * Bb + b) * (size_t)Cc * Nn;
#pragma unroll
  for (int g = 0; g < 2; ++g) {
    const float inv = 1.f / lrow[g];
    const int qn = wq0 + g * 16 + l15;
#pragma unroll
    for (int cb = 0; cb < 16; ++cb) {
#pragma unroll
      for (int r = 0; r < 4; ++r)
        Ob[(size_t)(cb * 16 + quad * 4 + r) * Nn + qn] = f2h(o[g][cb][r] * inv);
    }
  }
  if (lane < 16) {
    float* mlb = Ml + ((size_t)sp * Bb + b) * (size_t)Nn * 2;
#pragma unroll
    for (int g = 0; g < 2; ++g) {
      const int qn = wq0 + g * 16 + l15;
      *(f32x2*)(mlb + (size_t)qn * 2) = (f32x2){mrow[g], lrow[g]};
    }
  }
}

// ---------------------------------------------------------------------------
// Merge KSPLIT normalized fp16 partials: out = sum_s w_s*o_s,
// w_s = l_s*e^(m_s-m) / sum(l_s*e^(m_s-m)).
// ---------------------------------------------------------------------------
__global__ void merge_kernel(const u16* __restrict__ OpH,
                             const float* __restrict__ Ml,
                             float* __restrict__ out)
{
  const int idx = blockIdx.x * 256 + threadIdx.x;
  const int n4 = idx % 576;
  const int bc = idx / 576;
  const int b  = bc >> 8;
  const size_t obase = (size_t)bc * Nn + n4 * 4;

  float oh[KSPLIT][4], mv[KSPLIT][4], lv[KSPLIT][4];
#pragma unroll
  for (int s = 0; s < KSPLIT; ++s) {
    const u16x4 hv = *(const u16x4*)(OpH + ((size_t)s * Bb * Cc + bc) * Nn + n4 * 4);
#pragma unroll
    for (int j = 0; j < 4; ++j) oh[s][j] = h2f(hv[j]);
    const float* ml = Ml + ((size_t)s * Bb + b) * (size_t)Nn * 2 + n4 * 8;
    const f32x4 u0 = *(const f32x4*)ml;
    const f32x4 u1 = *(const f32x4*)(ml + 4);
#pragma unroll
    for (int j = 0; j < 4; ++j) {
      mv[s][j] = (j < 2) ? u0[j * 2]     : u1[(j - 2) * 2];
      lv[s][j] = (j < 2) ? u0[j * 2 + 1] : u1[(j - 2) * 2 + 1];
    }
  }

  f32x4 r;
#pragma unroll
  for (int j = 0; j < 4; ++j) {
    float m = mv[0][j];
#pragma unroll
    for (int s = 1; s < KSPLIT; ++s) m = fmaxf(m, mv[s][j]);
    float num = 0.f, den = 0.f;
#pragma unroll
    for (int s = 0; s < KSPLIT; ++s) {
      const float ws = lv[s][j] * exp2f((mv[s][j] - m) * L2E);
      num += oh[s][j] * ws;
      den += ws;
    }
    r[j] = num / den;
  }
  *(f32x4*)(out + obase) = r;
}

extern "C" void kernel_launch(void* const* d_in, const int* in_sizes, int n_in,
                              void* d_out, int out_size, void* d_ws, size_t ws_size,
                              hipStream_t stream) {
  const float* x  = (const float*)d_in[0];
  const float* y  = (const float*)d_in[1];
  const float* Wq = (const float*)d_in[2];
  const float* bq = (const float*)d_in[3];
  const float* Wk = (const float*)d_in[4];
  const float* bk = (const float*)d_in[5];
  const float* Wv = (const float*)d_in[6];
  const float* bv = (const float*)d_in[7];
  float* out = (float*)d_out;

  const size_t NC = (size_t)Bb * Nn * Cc;   // 4,718,592
  u16* Qf = (u16*)d_ws;
  u16* Kf = Qf + NC;
  u16* Vf = Kf + NC;
  u16* Wf = Vf + NC;
  u16* OpH = Wf + 3 * 65536;                  // fp16 normalized partials
  float* Ml = (float*)(OpH + (size_t)KSPLIT * NC);
  u16* Xt = (u16*)(Ml + (size_t)KSPLIT * Bb * Nn * 2);  // fp16 [B][N][C]
  u16* Yt = Xt + NC;

  hipLaunchKernelGGL(prep_kernel, dim3(2400), dim3(256), 0, stream,
                     Wq, Wk, Wv, x, y, Wf, Xt, Yt);
  hipLaunchKernelGGL(proj_kernel, dim3(Bb, PJT, 3), dim3(256), 0, stream,
                     Xt, Yt, Wf, bq, bk, bv, Qf, Kf, Vf);
  hipLaunchKernelGGL(attn_kernel, dim3(Bb, QT, KSPLIT), dim3(256), 0, stream,
                     Qf, Kf, Vf, OpH, Ml);
  hipLaunchKernelGGL(merge_kernel, dim3(4608), dim3(256), 0, stream,
                     OpH, Ml, out);
}

// Round 14
// 219.249 us; speedup vs baseline: 1.2050x; 1.2050x over previous
//
#include <hip/hip_runtime.h>
#include <stdint.h>

#define Bb 8
#define Cc 256
#define Nn 2304
#define PJT 18   // proj: 128-token tiles
#define QT 18    // attn: 128-query tiles
#define KSPLIT 3
#define TPS 24   // 32-key tiles per split (72 total / KSPLIT)
#define L2E 1.44269504088896f
#define DEFER_THR 8.0f

#define AS1 __attribute__((address_space(1)))
#define AS3 __attribute__((address_space(3)))

typedef unsigned short u16;
typedef unsigned int u32;
typedef _Float16 h16;
typedef h16  h16x8 __attribute__((ext_vector_type(8)));
typedef u16  u16x8 __attribute__((ext_vector_type(8)));
typedef u16  u16x4 __attribute__((ext_vector_type(4)));
typedef u32  u32x4 __attribute__((ext_vector_type(4)));
typedef float f32x4 __attribute__((ext_vector_type(4)));
typedef float f32x2 __attribute__((ext_vector_type(2)));

static __device__ __forceinline__ u16 f2h(float f) {
  return __builtin_bit_cast(u16, (h16)f);   // RTN
}
static __device__ __forceinline__ float h2f(u16 v) {
  return (float)__builtin_bit_cast(h16, v);
}
static __device__ __forceinline__ h16x8 ash(u16x8 v) {
  return __builtin_bit_cast(h16x8, v);
}
static __device__ __forceinline__ f32x4 mfma16(u16x8 a, u16x8 b, f32x4 c) {
  return __builtin_amdgcn_mfma_f32_16x16x32_f16(ash(a), ash(b), c, 0, 0, 0);
}
// pack 2 f32 -> 2 f16 (RTZ), as one u32 (P values only; P in [0, e^8])
static __device__ __forceinline__ u32 pkf16(float a, float b) {
  return __builtin_bit_cast(u32, __builtin_amdgcn_cvt_pkrtz(a, b));
}

// ---------------------------------------------------------------------------
// Prep v14 (verified r12): W fp32->fp16; x,y transpose to token-major fp16.
// ---------------------------------------------------------------------------
__global__ void prep_kernel(const float* __restrict__ Wq,
                            const float* __restrict__ Wk,
                            const float* __restrict__ Wv,
                            const float* __restrict__ x,
                            const float* __restrict__ y,
                            u16* __restrict__ Wf,
                            u16* __restrict__ Xt,
                            u16* __restrict__ Yt)
{
  const int bid = blockIdx.x;
  const int t   = threadIdx.x;
  if (bid < 96) {
    const int tid = bid * 256 + t;
    const int m   = tid >> 13;
    const int off = (tid & 8191) * 8;
    const float* src = (m == 0) ? Wq : (m == 1) ? Wk : Wv;
    const f32x4 a = *(const f32x4*)(src + off);
    const f32x4 c = *(const f32x4*)(src + off + 4);
    u16x8 o;
#pragma unroll
    for (int j = 0; j < 4; ++j) { o[j] = f2h(a[j]); o[j + 4] = f2h(c[j]); }
    *(u16x8*)(Wf + (size_t)m * 65536 + off) = o;
    return;
  }
  // transpose path: 2304 blocks = 2 tensors x 8 b x 36 tok-tiles x 4 c-tiles
  __shared__ u16 sT[64 * 64];   // 8 KB
  const int id2  = bid - 96;
  const float* src = (id2 < 1152) ? x : y;
  u16* dst         = (id2 < 1152) ? Xt : Yt;
  const int id3  = id2 % 1152;
  const int b    = id3 / 144;        // 144 = 36*4
  const int rem  = id3 % 144;
  const int tok0 = (rem >> 2) * 64;
  const int c0   = (rem & 3) * 64;

#pragma unroll
  for (int i = 0; i < 4; ++i) {
    const int id4 = i * 256 + t;
    const int cl  = id4 >> 4;        // channel-in-tile 0..63
    const int t4  = id4 & 15;        // token-quad 0..15
    const f32x4 v = *(const f32x4*)(src + ((size_t)b * Cc + c0 + cl) * Nn + tok0 + t4 * 4);
#pragma unroll
    for (int j = 0; j < 4; ++j) {
      const int tok = t4 * 4 + j;
      sT[tok * 64 + (cl ^ ((t4 & 7) << 3))] = f2h(v[j]);  // t4 == tok>>2
    }
  }
  __syncthreads();
#pragma unroll
  for (int i = 0; i < 2; ++i) {
    const int id5 = i * 256 + t;
    const int tok = id5 >> 3;        // 0..63
    const int c8  = (id5 & 7) * 8;
    const u16x8 vv = *(const u16x8*)(sT + tok * 64 + (c8 ^ (((tok >> 2) & 7) << 3)));
    *(u16x8*)(dst + ((size_t)b * Nn + tok0 + tok) * Cc + c0 + c8) = vv;
  }
}

// ---------------------------------------------------------------------------
// Projection v14 (verified r12): 4-round dbuf DMA-staged W, two 64-token
// groups per wave, contiguous af loads from Xt/Yt, coalesced LDS-bounce
// epilogue.
// ---------------------------------------------------------------------------
__global__ __launch_bounds__(256, 2) void proj_kernel(
    const u16* __restrict__ Xt, const u16* __restrict__ Yt,
    const u16* __restrict__ Wf,
    const float* __restrict__ bq, const float* __restrict__ bk,
    const float* __restrict__ bv,
    u16* __restrict__ Qf, u16* __restrict__ Kf, u16* __restrict__ Vf)
{
  __shared__ u16 sW[2][64 * 256];   // 2 x 32 KB
  const int t    = threadIdx.x;
  const int b    = blockIdx.x;
  const int q0   = blockIdx.y * 128;
  const int z    = blockIdx.z;
  const int lane = t & 63;
  const int w    = t >> 6;
  const int quad = lane >> 4;
  const int l15  = lane & 15;

  const u16* WZ = Wf + (size_t)z * 65536;

  const int rbase = 2 * w + (lane >> 5);
  const int wcol  = ((lane & 31) ^ rbase) << 3;

  auto stage = [&](int rg, int buf) {
#pragma unroll
    for (int it = 0; it < 8; ++it) {
      __builtin_amdgcn_global_load_lds(
          (const AS1 void*)(WZ + (size_t)(rg * 64 + rbase + 8 * it) * 256 + wcol),
          (AS3 void*)&sW[buf][(w + 4 * it) * 512], 16, 0, 0);
    }
  };

  stage(0, 0);   // overlap W DMA with the token-fragment loads below

  // token fragments, two 64-token groups: contiguous u16x8 from Xt/Yt
  const u16* S = (z == 0) ? Xt : Yt;
  u16x8 af[2][8];
#pragma unroll
  for (int g = 0; g < 2; ++g) {
    const size_t row = ((size_t)b * Nn + q0 + g * 64 + w * 16 + l15) * Cc;
#pragma unroll
    for (int kc = 0; kc < 8; ++kc)
      af[g][kc] = *(const u16x8*)(S + row + kc * 32 + quad * 8);
  }

  f32x4 acc[2][16];
#pragma unroll
  for (int g = 0; g < 2; ++g)
#pragma unroll
    for (int i = 0; i < 16; ++i) acc[g][i] = (f32x4){0.f, 0.f, 0.f, 0.f};

  int cur = 0;
#pragma unroll 1
  for (int rg = 0; rg < 4; ++rg) {   // 64 c_out rows per round
    __builtin_amdgcn_s_waitcnt(0x0F70);  // vmcnt(0): sW[cur] DMA done
    __syncthreads();                     // visible to all; prev round's reads done
    if (rg + 1 < 4) stage(rg + 1, cur ^ 1);   // hides under this round's compute
#pragma unroll
    for (int cbl = 0; cbl < 4; ++cbl) {
      const int rl = cbl * 16 + l15;   // 0..63
      f32x4 a0 = acc[0][rg * 4 + cbl];
      f32x4 a1 = acc[1][rg * 4 + cbl];
#pragma unroll
      for (int kc = 0; kc < 8; ++kc) {
        const u16x8 bf = *(const u16x8*)(sW[cur] + rl * 256 + (((kc * 4 + quad) ^ (rl & 7)) << 3));
        if (z < 2) {
          a0 = mfma16(af[0][kc], bf, a0);
          a1 = mfma16(af[1][kc], bf, a1);
        } else {
          a0 = mfma16(bf, af[0][kc], a0);
          a1 = mfma16(bf, af[1][kc], a1);
        }
      }
      acc[0][rg * 4 + cbl] = a0;
      acc[1][rg * 4 + cbl] = a1;
    }
    cur ^= 1;
  }

  // ---- coalesced epilogues via LDS bounce (sT = 32 KB within sW) ----
  u16* sT = &sW[0][0];
  if (z < 2) {
    const float* bias = (z == 0) ? bq : bk;
    u16* O = (z == 0) ? Qf : Kf;
#pragma unroll
    for (int g = 0; g < 2; ++g) {
      __syncthreads();   // prior users of sW done (compute rounds / prev g copy)
#pragma unroll
      for (int cb = 0; cb < 16; ++cb) {
        const int col = cb * 16 + l15;
        const float bs = bias[col];
#pragma unroll
        for (int r = 0; r < 4; ++r) {
          const int row = w * 16 + quad * 4 + r;   // token-in-tile 0..63
          sT[row * 256 + (col ^ ((row & 7) << 3))] = f2h(acc[g][cb][r] + bs);
        }
      }
      __syncthreads();
      const size_t ob = ((size_t)b * Nn + q0 + g * 64) * Cc;
#pragma unroll
      for (int i = 0; i < 8; ++i) {
        const int lin = i * 256 + t;
        const int row = lin >> 5, ch = lin & 31;
        const u16x8 v = *(const u16x8*)(sT + row * 256 + ((ch ^ (row & 7)) << 3));
        *(u16x8*)(O + ob + (size_t)lin * 8) = v;
      }
    }
  } else {
#pragma unroll
    for (int g = 0; g < 2; ++g) {
      __syncthreads();
#pragma unroll
      for (int cb = 0; cb < 16; ++cb) {
#pragma unroll
        for (int r = 0; r < 4; ++r) {
          const int c = cb * 16 + quad * 4 + r;    // c_out row 0..255
          const int col = w * 16 + l15;            // token-in-tile 0..63
          sT[c * 64 + (col ^ ((c & 7) << 3))] = f2h(acc[g][cb][r] + bv[c]);
        }
      }
      __syncthreads();
#pragma unroll
      for (int i = 0; i < 8; ++i) {
        const int lin = i * 256 + t;
        const int row = lin >> 3, g8 = lin & 7;
        const u16x8 v = *(const u16x8*)(sT + row * 64 + ((g8 ^ (row & 7)) << 3));
        *(u16x8*)(Vf + ((size_t)b * Cc + row) * Nn + q0 + g * 64 + g8 * 8) = v;
      }
    }
  }
}

// ---------------------------------------------------------------------------
// Flash attention v16 = v13 (REVERTED: K in LDS via kappa-permuted DMA —
// r13 proved direct-global K is L2-hit-latency-bound: 75.7->119 µs with
// FETCH unchanged and conflicts 0. K/V LDS staging + DMA prefetch is a
// kernel invariant now) + ONE isolated variable: s_setprio(1) around the
// two MFMA clusters (no reordering, no live-range change — r8's regression
// was spill from reordering, proven by FETCH/WRITE jump; T5 measured +4-7%
// on attn with co-resident blocks at different phases).
// ---------------------------------------------------------------------------
__global__ __launch_bounds__(256, 2) void attn_kernel(
    const u16* __restrict__ Qf, const u16* __restrict__ Kf,
    const u16* __restrict__ Vf, u16* __restrict__ OpH,
    float* __restrict__ Ml)
{
  __shared__ u16 sK[2][32 * 256];   // 2 x 16 KB
  __shared__ u16 sV[2][256 * 32];   // 2 x 16 KB
  const int t    = threadIdx.x;
  const int b    = blockIdx.x;
  const int q0   = blockIdx.y * 128;
  const int sp   = blockIdx.z;
  const int lane = t & 63;
  const int w    = t >> 6;
  const int quad = lane >> 4;
  const int l15  = lane & 15;
  const int wq0  = q0 + w * 32;

  const u16* Kb = Kf + (size_t)b * Nn * Cc;
  const u16* Vb = Vf + (size_t)b * Cc * Nn;

  // DMA staging geometry (kappa-permuted K rows)
  const int rbase = 2 * w + (lane >> 5);
  const int kcol  = ((lane & 31) ^ rbase) << 3;
  const int rb2 = rbase >> 2, rb3 = rbase & 3;
  int koff[4];
#pragma unroll
  for (int it = 0; it < 4; ++it) {
    const int key = (((rb2 + 2 * it) & 3) << 3) + rb3 + ((it >> 1) << 2);
    koff[it] = key * Cc + kcol;
  }
  const u16* Kt = Kb + (size_t)(sp * TPS * 32) * Cc;
  const int cV   = w * 16 + (lane >> 2);
  const int vcol = ((lane & 3) ^ ((cV >> 1) & 3)) << 3;
  const u16* vp0 = Vb + (size_t)cV * Nn + sp * TPS * 32 + vcol;

  auto stage = [&](int kb, int buf) {
#pragma unroll
    for (int it = 0; it < 4; ++it) {
      __builtin_amdgcn_global_load_lds(
          (const AS1 void*)(Kt + (size_t)kb * 32 * Cc + koff[it]),
          (AS3 void*)&sK[buf][(w + 4 * it) * 512], 16, 0, 0);
      __builtin_amdgcn_global_load_lds(
          (const AS1 void*)(vp0 + kb * 32 + (size_t)it * 64 * Nn),
          (AS3 void*)&sV[buf][(w + 4 * it) * 512], 16, 0, 0);
    }
  };

  stage(0, 0);   // overlap with qf loads

  // Q fragments, 2 groups of 16 queries (B-operand; col = lane = query)
  u16x8 qf[2][8];
#pragma unroll
  for (int g = 0; g < 2; ++g) {
    const size_t qrow = ((size_t)b * Nn + wq0 + g * 16 + l15) * Cc;
#pragma unroll
    for (int kc = 0; kc < 8; ++kc)
      qf[g][kc] = *(const u16x8*)(Qf + qrow + kc * 32 + quad * 8);
  }

  f32x4 o[2][16];   // O^T accum per group: c = cb*16+quad*4+r, q = l15
#pragma unroll
  for (int g = 0; g < 2; ++g)
#pragma unroll
    for (int i = 0; i < 16; ++i) o[g][i] = (f32x4){0.f, 0.f, 0.f, 0.f};
  float mrow[2] = {-3e38f, -3e38f};
  float lrow[2] = {0.f, 0.f};

  // PV read swizzle is cb-independent: (c>>1)&3 == (l15>>1)&3
  const int vbase = l15 * 32 + ((quad ^ ((l15 >> 1) & 3)) << 3);

  int cur = 0;
#pragma unroll 1
  for (int kb = 0; kb < TPS; ++kb) {
    __builtin_amdgcn_s_waitcnt(0x0F70);  // vmcnt(0): sK/sV[cur] DMA done
    __syncthreads();                     // visible; prev tile's reads all done

    // ---- S^T = K Q^T, both query groups share k0/k1 reads
    f32x4 s[2][2];
    s[0][0] = (f32x4){0.f, 0.f, 0.f, 0.f}; s[0][1] = s[0][0];
    s[1][0] = s[0][0];                      s[1][1] = s[0][0];
    __builtin_amdgcn_s_setprio(1);
#pragma unroll
    for (int kc = 0; kc < 8; ++kc) {
      const int ch = ((kc * 4 + quad) ^ (l15 & 7)) << 3;
      const u16x8 k0 = *(const u16x8*)(sK[cur] + l15 * 256 + ch);
      const u16x8 k1 = *(const u16x8*)(sK[cur] + (16 + l15) * 256 + ch);
      s[0][0] = mfma16(k0, qf[0][kc], s[0][0]);
      s[0][1] = mfma16(k1, qf[0][kc], s[0][1]);
      s[1][0] = mfma16(k0, qf[1][kc], s[1][0]);
      s[1][1] = mfma16(k1, qf[1][kc], s[1][1]);
    }
    __builtin_amdgcn_s_setprio(0);

    // ---- prefetch next tile (off the critical prefix; lands under PV)
    if (kb + 1 < TPS) stage(kb + 1, cur ^ 1);

    // ---- lane-local online softmax per group
    u16x8 pf[2];
    float al[2];
    int needany = 0;
#pragma unroll
    for (int g = 0; g < 2; ++g) {
      float mloc = fmaxf(
          fmaxf(fmaxf(s[g][0][0], s[g][0][1]), fmaxf(s[g][0][2], s[g][0][3])),
          fmaxf(fmaxf(s[g][1][0], s[g][1][1]), fmaxf(s[g][1][2], s[g][1][3])));
      mloc = fmaxf(mloc, __shfl_xor(mloc, 16, 64));
      mloc = fmaxf(mloc, __shfl_xor(mloc, 32, 64));
      const bool need = mloc > mrow[g] + DEFER_THR;
      const float mn  = need ? mloc : mrow[g];
      al[g] = need ? exp2f((mrow[g] - mn) * L2E) : 1.f;
      mrow[g] = mn;
      needany |= (int)need;

      float p[8];
      float sum = 0.f;
#pragma unroll
      for (int r = 0; r < 4; ++r) {
        p[r]     = exp2f((s[g][0][r] - mn) * L2E);
        p[4 + r] = exp2f((s[g][1][r] - mn) * L2E);
        sum += p[r] + p[4 + r];
      }
      sum += __shfl_xor(sum, 16, 64);
      sum += __shfl_xor(sum, 32, 64);
      lrow[g] = lrow[g] * al[g] + sum;

      u32x4 pw;
      pw[0] = pkf16(p[0], p[1]);
      pw[1] = pkf16(p[2], p[3]);
      pw[2] = pkf16(p[4], p[5]);
      pw[3] = pkf16(p[6], p[7]);
      pf[g] = __builtin_bit_cast(u16x8, pw);
    }

    if (__any(needany)) {
#pragma unroll
      for (int i = 0; i < 16; ++i) {
#pragma unroll
        for (int r = 0; r < 4; ++r) {
          o[0][i][r] *= al[0];
          o[1][i][r] *= al[1];
        }
      }
    }

    // ---- O^T += V^T P, both groups share vf reads
    __builtin_amdgcn_s_setprio(1);
#pragma unroll
    for (int cb = 0; cb < 16; ++cb) {
      const u16x8 vf = *(const u16x8*)(sV[cur] + cb * 512 + vbase);
      o[0][cb] = mfma16(vf, pf[0], o[0][cb]);
      o[1][cb] = mfma16(vf, pf[1], o[1][cb]);
    }
    __builtin_amdgcn_s_setprio(0);

    cur ^= 1;
  }

  // ---- epilogue: per-split NORMALIZED fp16 partials
  u16* Ob = OpH + ((size_t)sp * Bb + b) * (size_t)Cc * Nn;
#pragma unroll
  for (int g = 0; g < 2; ++g) {
    const float inv = 1.f / lrow[g];
    const int qn = wq0 + g * 16 + l15;
#pragma unroll
    for (int cb = 0; cb < 16; ++cb) {
#pragma unroll
      for (int r = 0; r < 4; ++r)
        Ob[(size_t)(cb * 16 + quad * 4 + r) * Nn + qn] = f2h(o[g][cb][r] * inv);
    }
  }
  if (lane < 16) {
    float* mlb = Ml + ((size_t)sp * Bb + b) * (size_t)Nn * 2;
#pragma unroll
    for (int g = 0; g < 2; ++g) {
      const int qn = wq0 + g * 16 + l15;
      *(f32x2*)(mlb + (size_t)qn * 2) = (f32x2){mrow[g], lrow[g]};
    }
  }
}

// ---------------------------------------------------------------------------
// Merge KSPLIT normalized fp16 partials: out = sum_s w_s*o_s,
// w_s = l_s*e^(m_s-m) / sum(l_s*e^(m_s-m)).
// ---------------------------------------------------------------------------
__global__ void merge_kernel(const u16* __restrict__ OpH,
                             const float* __restrict__ Ml,
                             float* __restrict__ out)
{
  const int idx = blockIdx.x * 256 + threadIdx.x;
  const int n4 = idx % 576;
  const int bc = idx / 576;
  const int b  = bc >> 8;
  const size_t obase = (size_t)bc * Nn + n4 * 4;

  float oh[KSPLIT][4], mv[KSPLIT][4], lv[KSPLIT][4];
#pragma unroll
  for (int s = 0; s < KSPLIT; ++s) {
    const u16x4 hv = *(const u16x4*)(OpH + ((size_t)s * Bb * Cc + bc) * Nn + n4 * 4);
#pragma unroll
    for (int j = 0; j < 4; ++j) oh[s][j] = h2f(hv[j]);
    const float* ml = Ml + ((size_t)s * Bb + b) * (size_t)Nn * 2 + n4 * 8;
    const f32x4 u0 = *(const f32x4*)ml;
    const f32x4 u1 = *(const f32x4*)(ml + 4);
#pragma unroll
    for (int j = 0; j < 4; ++j) {
      mv[s][j] = (j < 2) ? u0[j * 2]     : u1[(j - 2) * 2];
      lv[s][j] = (j < 2) ? u0[j * 2 + 1] : u1[(j - 2) * 2 + 1];
    }
  }

  f32x4 r;
#pragma unroll
  for (int j = 0; j < 4; ++j) {
    float m = mv[0][j];
#pragma unroll
    for (int s = 1; s < KSPLIT; ++s) m = fmaxf(m, mv[s][j]);
    float num = 0.f, den = 0.f;
#pragma unroll
    for (int s = 0; s < KSPLIT; ++s) {
      const float ws = lv[s][j] * exp2f((mv[s][j] - m) * L2E);
      num += oh[s][j] * ws;
      den += ws;
    }
    r[j] = num / den;
  }
  *(f32x4*)(out + obase) = r;
}

extern "C" void kernel_launch(void* const* d_in, const int* in_sizes, int n_in,
                              void* d_out, int out_size, void* d_ws, size_t ws_size,
                              hipStream_t stream) {
  const float* x  = (const float*)d_in[0];
  const float* y  = (const float*)d_in[1];
  const float* Wq = (const float*)d_in[2];
  const float* bq = (const float*)d_in[3];
  const float* Wk = (const float*)d_in[4];
  const float* bk = (const float*)d_in[5];
  const float* Wv = (const float*)d_in[6];
  const float* bv = (const float*)d_in[7];
  float* out = (float*)d_out;

  const size_t NC = (size_t)Bb * Nn * Cc;   // 4,718,592
  u16* Qf = (u16*)d_ws;
  u16* Kf = Qf + NC;
  u16* Vf = Kf + NC;
  u16* Wf = Vf + NC;
  u16* OpH = Wf + 3 * 65536;                  // fp16 normalized partials
  float* Ml = (float*)(OpH + (size_t)KSPLIT * NC);
  u16* Xt = (u16*)(Ml + (size_t)KSPLIT * Bb * Nn * 2);  // fp16 [B][N][C]
  u16* Yt = Xt + NC;

  hipLaunchKernelGGL(prep_kernel, dim3(2400), dim3(256), 0, stream,
                     Wq, Wk, Wv, x, y, Wf, Xt, Yt);
  hipLaunchKernelGGL(proj_kernel, dim3(Bb, PJT, 3), dim3(256), 0, stream,
                     Xt, Yt, Wf, bq, bk, bv, Qf, Kf, Vf);
  hipLaunchKernelGGL(attn_kernel, dim3(Bb, QT, KSPLIT), dim3(256), 0, stream,
                     Qf, Kf, Vf, OpH, Ml);
  hipLaunchKernelGGL(merge_kernel, dim3(4608), dim3(256), 0, stream,
                     OpH, Ml, out);
}